// Round 4
// baseline (10654.057 us; speedup 1.0000x reference)
//
#include <hip/hip_runtime.h>
#include <cmath>

typedef __bf16 bf16x8 __attribute__((ext_vector_type(8)));
typedef float  f32x4  __attribute__((ext_vector_type(4)));
typedef unsigned int u32;
typedef unsigned long long u64;
typedef u32 u32x4v __attribute__((ext_vector_type(4)));

#define T_STEPS 1024
#define I_DIM   256
#define H_DIM   512
#define B_TOT   64
#define NBT     8     // batch tiles = communication domains; bid&7 -> XCD (if round-robin)
#define NCT     16    // column tiles per domain (16 WGs/domain -> one residue class)
#define BT      8     // batches per tile (MFMA M=8 of 16 rows used; MFMA util is ~1%, waste is free)
#define CT      32    // columns per gate per WG
#define FDOM    64    // flag slots per domain: slot = producer_j*4 + wave
#define WPB     (H_DIM / 2)            // u64 LL words per batch row (2 bf16 + tag per word)
#define LLW     (2 * NBT * BT * WPB)   // u64 words per exchange buffer (both parities)

__device__ __forceinline__ f32x4 mfma16(bf16x8 a, bf16x8 b, f32x4 c) {
    return __builtin_amdgcn_mfma_f32_16x16x32_bf16(a, b, c, 0, 0, 0);
}

// two float4 registers -> bf16x8 A-fragment (pure VALU, no loads)
__device__ __forceinline__ bf16x8 cvt8r(float4 a, float4 b) {
    bf16x8 f;
    f[0] = (__bf16)a.x; f[1] = (__bf16)a.y; f[2] = (__bf16)a.z; f[3] = (__bf16)a.w;
    f[4] = (__bf16)b.x; f[5] = (__bf16)b.y; f[6] = (__bf16)b.z; f[7] = (__bf16)b.w;
    return f;
}

// ---- agent-scope (device-coherent, IF$-serviced) primitives — round-0 proven ----
__device__ __forceinline__ int ld_flag(const int* p) {
    return __hip_atomic_load(p, __ATOMIC_RELAXED, __HIP_MEMORY_SCOPE_AGENT);
}
__device__ __forceinline__ void st_flag(int* p, int v) {
    __hip_atomic_store(p, v, __ATOMIC_RELAXED, __HIP_MEMORY_SCOPE_AGENT);
}
__device__ __forceinline__ u64 ld_u64(const u64* p) {
    return __hip_atomic_load(p, __ATOMIC_RELAXED, __HIP_MEMORY_SCOPE_AGENT);
}
__device__ __forceinline__ void st_u64(u64* p, u64 v) {
    __hip_atomic_store(p, v, __ATOMIC_RELAXED, __HIP_MEMORY_SCOPE_AGENT);
}

// ---- sc0 (L1-bypass, L2-served) fast-path loads ----
__device__ __forceinline__ int ld_flag_sc0(const int* p) {
    int v;
    asm volatile("global_load_dword %0, %1, off sc0\n\ts_waitcnt vmcnt(0)"
                 : "=v"(v) : "v"(p) : "memory");
    return v;
}
__device__ __forceinline__ void ld2_sc0(const u64* p, u64& d) {
    asm volatile("global_load_dwordx2 %0, %1, off sc0" : "=v"(d) : "v"(p) : "memory");
}

// wait on all 64 per-(producer,wave) flags of a domain.
// Fast phase: sc0 polls (L2). Timeout -> latch remote -> agent polls (IF$).
// Flags are advisory for the fast DATA path (tags validate); agent phase is exact.
__device__ __forceinline__ void wait64(const int* fdom, int target, bool& rem) {
    const int* p = fdom + (threadIdx.x & 63);
    if (!rem) {
        for (int g = 0; g < 64; ++g) {
            int v = ld_flag_sc0(p);
            if (__ballot(v >= target) == ~0ull) return;
        }
        rem = true;
    }
    for (int g = 0; g < (1 << 22); ++g) {
        int v = ld_flag(p);
        if (__ballot(v >= target) == ~0ull) break;
    }
    asm volatile("" ::: "memory");
}

// Load this wave's 16 LL words (4 k-chunks x 4 words) for one exchange.
// Fast: one-shot sc0 loads + tag check (bounded retries, then latch remote).
// Remote: agent loads — flag-gated, guaranteed fresh (round-0 semantics).
__device__ __forceinline__ void load16(const u64* base, int w, int q, u32 tag,
                                       u64* wd, bool& rem) {
    if (!rem) {
        for (int r = 0; r < 8; ++r) {
            #pragma unroll
            for (int s = 0; s < 4; ++s) {
                const u64* ptr = base + (w + 4 * s) * 16 + q * 4;
                ld2_sc0(ptr + 0, wd[4*s+0]);
                ld2_sc0(ptr + 1, wd[4*s+1]);
                ld2_sc0(ptr + 2, wd[4*s+2]);
                ld2_sc0(ptr + 3, wd[4*s+3]);
            }
            asm volatile("s_waitcnt vmcnt(0)" ::: "memory");
            __builtin_amdgcn_sched_barrier(0);
            bool ok = true;
            #pragma unroll
            for (int x = 0; x < 16; ++x) ok &= ((u32)(wd[x] >> 32) == tag);
            if (__ballot(ok) == ~0ull) return;
            __builtin_amdgcn_s_sleep(4);
        }
        rem = true;
    }
    #pragma unroll
    for (int s = 0; s < 4; ++s) {
        const u64* ptr = base + (w + 4 * s) * 16 + q * 4;
        #pragma unroll
        for (int k = 0; k < 4; ++k) wd[4*s+k] = ld_u64(ptr + k);
    }
}

// 4 LL words -> bf16x8 A-fragment (low 32 bits of each word = 2 bf16 cols)
__device__ __forceinline__ bf16x8 frag_of(const u64* wrd) {
    u32x4v d;
    d.x = (u32)wrd[0]; d.y = (u32)wrd[1]; d.z = (u32)wrd[2]; d.w = (u32)wrd[3];
    return __builtin_bit_cast(bf16x8, d);
}

// Persistent GRU. Grid: 128 WGs = 8 domains (batch-tiles, XCD-pure if round-robin)
// x 16 column-tiles, 256 thr (4 waves). Wave w owns K-chunks kk = w + 4s (s=0..5)
// of K=768 ([x(256); h(512)]). Round-0 compute mapping (4-wave K-split + LDS
// reduce); per-(producer,wave) flags drop the publish barriers (2 barriers/step).
__global__ __launch_bounds__(256, 1) void gru_persist(
    const float* __restrict__ xs,
    const float* __restrict__ Wz, const float* __restrict__ bz,
    const float* __restrict__ Wr, const float* __restrict__ br,
    const float* __restrict__ Wh, const float* __restrict__ bh,
    float* __restrict__ out,
    u64* hll, u64* rhll, int* flag_h, int* flag_r)
{
    const int bid  = blockIdx.x;
    const int i    = bid & (NBT - 1);   // domain = XCD residue
    const int j    = bid >> 3;          // column tile 0..15
    const int tid  = threadIdx.x;
    const int w    = tid >> 6;
    const int lane = tid & 63;
    const int q    = lane >> 4;
    const int ln   = lane & 15;
    const int cb   = j * CT;

    __shared__ float red1[2][4][8][33];
    __shared__ float red2[4][8][33];

    // ---- stationary weight B-fragments: per k-chunk s, per N-tile n ----
    bf16x8 WZ[6][2], WR[6][2], WH[6][2];
    #pragma unroll
    for (int s = 0; s < 6; ++s) {
        int krow = (w + 4 * s) * 32 + q * 8;
        #pragma unroll
        for (int n = 0; n < 2; ++n) {
            bf16x8 fz, fr, fh;
            #pragma unroll
            for (int jj = 0; jj < 8; ++jj) {
                int off = (krow + jj) * H_DIM + cb + n * 16 + ln;
                fz[jj] = (__bf16)Wz[off];
                fr[jj] = (__bf16)Wr[off];
                fh[jj] = (__bf16)Wh[off];
            }
            WZ[s][n] = fz; WR[s][n] = fr; WH[s][n] = fh;
        }
    }

    const int m = tid >> 5;        // epilogue thread -> (batch m 0..7, col c 0..31)
    const int c = tid & 31;
    const float bzc = bz[cb + c], brc = br[cb + c], bhc = bh[cb + c];
    float hprev = 0.0f;

    const float* xrow = xs + (size_t)(i * BT + (ln & 7)) * T_STEPS * I_DIM;
    int* fh_dom = flag_h + i * FDOM;
    int* fr_dom = flag_r + i * FDOM;

    bool remh = false, remr = false;   // per-exchange remote latches (wave-uniform)

    // x fragments for current step held in registers (chunks kk=w and kk=w+4)
    float4 xst[4];
    {
        const float* x0 = xrow;
        xst[0] = *(const float4*)(x0 + (w    ) * 32 + q * 8);
        xst[1] = *(const float4*)(x0 + (w    ) * 32 + q * 8 + 4);
        xst[2] = *(const float4*)(x0 + (w + 4) * 32 + q * 8);
        xst[3] = *(const float4*)(x0 + (w + 4) * 32 + q * 8 + 4);
    }

    for (int t = 0; t < T_STEPS; ++t) {
        const int p = t & 1, pp = p ^ 1;

        // ---- issue x prefetch for t+1 (retires during this step) ----
        float4 xn[4];
        {
            int tn = (t + 1 < T_STEPS) ? t + 1 : t;
            const float* xp = xrow + (size_t)tn * I_DIM;
            xn[0] = *(const float4*)(xp + (w    ) * 32 + q * 8);
            xn[1] = *(const float4*)(xp + (w    ) * 32 + q * 8 + 4);
            xn[2] = *(const float4*)(xp + (w + 4) * 32 + q * 8);
            xn[3] = *(const float4*)(xp + (w + 4) * 32 + q * 8 + 4);
        }

        f32x4 accz[2] = {{0,0,0,0},{0,0,0,0}};
        f32x4 accr[2] = {{0,0,0,0},{0,0,0,0}};
        f32x4 acch[2] = {{0,0,0,0},{0,0,0,0}};

        // x-part MFMAs from registers (no recurrence dep)
        {
            bf16x8 ax0 = cvt8r(xst[0], xst[1]);
            bf16x8 ax1 = cvt8r(xst[2], xst[3]);
            #pragma unroll
            for (int n = 0; n < 2; ++n) {
                accz[n] = mfma16(ax0, WZ[0][n], accz[n]);
                accr[n] = mfma16(ax0, WR[0][n], accr[n]);
                acch[n] = mfma16(ax0, WH[0][n], acch[n]);
                accz[n] = mfma16(ax1, WZ[1][n], accz[n]);
                accr[n] = mfma16(ax1, WR[1][n], accr[n]);
                acch[n] = mfma16(ax1, WH[1][n], acch[n]);
            }
        }

        // ---- stage 1: wait h_{t-1}, load frags (L2 fast / IF$ fallback), z+r MFMAs ----
        {
            wait64(fh_dom, t, remh);
            const u64* hb = hll + ((size_t)((pp * NBT + i) * BT) + (ln & 7)) * WPB;
            u64 wd[16];
            load16(hb, w, q, (u32)t, wd, remh);
            #pragma unroll
            for (int s = 0; s < 4; ++s) {
                bf16x8 ah = frag_of(&wd[4 * s]);
                #pragma unroll
                for (int n = 0; n < 2; ++n) {
                    accz[n] = mfma16(ah, WZ[s + 2][n], accz[n]);
                    accr[n] = mfma16(ah, WR[s + 2][n], accr[n]);
                }
            }
        }

        if (q < 2) {
            #pragma unroll
            for (int n = 0; n < 2; ++n)
                #pragma unroll
                for (int r4 = 0; r4 < 4; ++r4) {
                    red1[0][w][q * 4 + r4][n * 16 + ln] = accz[n][r4];
                    red1[1][w][q * 4 + r4][n * 16 + ln] = accr[n][r4];
                }
        }
        __syncthreads();                                         // S1

        // stage-1 epilogue: z, r, publish r*h (tagged words, per-wave drain+flag)
        float zv;
        {
            float pz = red1[0][0][m][c] + red1[0][1][m][c] + red1[0][2][m][c] + red1[0][3][m][c] + bzc;
            float pr = red1[1][0][m][c] + red1[1][1][m][c] + red1[1][2][m][c] + red1[1][3][m][c] + brc;
            zv = 1.0f / (1.0f + __expf(-pz));
            float rv = 1.0f / (1.0f + __expf(-pr));
            unsigned short v16 = __builtin_bit_cast(unsigned short, (__bf16)(rv * hprev));
            unsigned short nb  = (unsigned short)__shfl((int)v16, lane + 1);
            if (!(c & 1)) {
                u64 wrd = (u64)((u32)v16 | ((u32)nb << 16)) | ((u64)(u32)(t + 1) << 32);
                st_u64(rhll + ((size_t)((p * NBT + i) * BT) + m) * WPB + ((cb + c) >> 1), wrd);
            }
            asm volatile("s_waitcnt vmcnt(0)" ::: "memory");     // per-wave store drain
            if (lane == 0) st_flag(fr_dom + j * 4 + w, t + 1);
        }

        // ---- stage 2: wait r⊙h, load frags, h~ MFMAs ----
        {
            wait64(fr_dom, t + 1, remr);
            const u64* rb = rhll + ((size_t)((p * NBT + i) * BT) + (ln & 7)) * WPB;
            u64 we[16];
            load16(rb, w, q, (u32)(t + 1), we, remr);
            #pragma unroll
            for (int s = 0; s < 4; ++s) {
                bf16x8 ar_ = frag_of(&we[4 * s]);
                #pragma unroll
                for (int n = 0; n < 2; ++n)
                    acch[n] = mfma16(ar_, WH[s + 2][n], acch[n]);
            }
        }

        if (q < 2) {
            #pragma unroll
            for (int n = 0; n < 2; ++n)
                #pragma unroll
                for (int r4 = 0; r4 < 4; ++r4)
                    red2[w][q * 4 + r4][n * 16 + ln] = acch[n][r4];
        }
        __syncthreads();                                         // S2

        // stage-2 epilogue: h~, h_t, publish h; out[] after the flag
        {
            float ph  = red2[0][m][c] + red2[1][m][c] + red2[2][m][c] + red2[3][m][c] + bhc;
            float e2  = __expf(2.0f * ph);
            float htl = (e2 - 1.0f) / (e2 + 1.0f);
            float hn  = (1.0f - zv) * hprev + zv * htl;
            hprev = hn;

            unsigned short v16 = __builtin_bit_cast(unsigned short, (__bf16)hn);
            unsigned short nb  = (unsigned short)__shfl((int)v16, lane + 1);
            if (!(c & 1)) {
                u64 wrd = (u64)((u32)v16 | ((u32)nb << 16)) | ((u64)(u32)(t + 1) << 32);
                st_u64(hll + ((size_t)((p * NBT + i) * BT) + m) * WPB + ((cb + c) >> 1), wrd);
            }
            asm volatile("s_waitcnt vmcnt(0)" ::: "memory");     // per-wave store drain
            if (lane == 0) st_flag(fh_dom + j * 4 + w, t + 1);

            // off-critical-path output stores
            int bglob = i * BT + m;
            out[((size_t)bglob * T_STEPS + t) * H_DIM + cb + c] = hn;
            if (t == T_STEPS - 1)
                out[(size_t)B_TOT * T_STEPS * H_DIM + (size_t)bglob * H_DIM + cb + c] = hn;
        }

        xst[0] = xn[0]; xst[1] = xn[1]; xst[2] = xn[2]; xst[3] = xn[3];
    }
}

extern "C" void kernel_launch(void* const* d_in, const int* in_sizes, int n_in,
                              void* d_out, int out_size, void* d_ws, size_t ws_size,
                              hipStream_t stream)
{
    const float* xs = (const float*)d_in[0];
    const float* Wz = (const float*)d_in[1];
    const float* bz = (const float*)d_in[2];
    const float* Wr = (const float*)d_in[3];
    const float* br = (const float*)d_in[4];
    const float* Wh = (const float*)d_in[5];
    const float* bh = (const float*)d_in[6];
    float* out = (float*)d_out;

    // ws: hll[2][8][8][256] u64 (256KB) | rhll (256KB) |
    //     flag_h[8][64] int (2KB) | flag_r[8][64] int (2KB)
    u64* hll  = (u64*)d_ws;
    u64* rhll = hll + LLW;
    int* flag_h = (int*)((char*)d_ws + 2 * LLW * sizeof(u64));
    int* flag_r = flag_h + NBT * FDOM;

    hipMemsetAsync(d_ws, 0, 2 * LLW * sizeof(u64) + 2 * NBT * FDOM * sizeof(int), stream);
    gru_persist<<<dim3(NBT * NCT), dim3(256), 0, stream>>>(
        xs, Wz, bz, Wr, br, Wh, bh, out, hll, rhll, flag_h, flag_r);
}